// Round 4
// baseline (653.237 us; speedup 1.0000x reference)
//
#include <hip/hip_runtime.h>

typedef unsigned short u16;
typedef unsigned int u32;
typedef __attribute__((ext_vector_type(8))) short short8;
typedef __attribute__((ext_vector_type(4))) float floatx4;

static constexpr int M = 16384, N = 2048, K = 2048;

// ---- helpers -------------------------------------------------------------

__device__ inline u16 f32_to_bf16(float x) {
    u32 u = __float_as_uint(x);
    u += 0x7FFFu + ((u >> 16) & 1u);
    return (u16)(u >> 16);
}

// RNE round to e4m3 grid; valid for x in [2^-6, 448] (normal e4m3 range,
// guaranteed by the preceding clip). 3 mantissa bits -> round at fp32 bit 20.
__device__ inline float e4m3_rne(float x) {
    u32 u = __float_as_uint(x);
    u += 0x7FFFFu + ((u >> 20) & 1u);
    u &= 0xFFF00000u;
    return __uint_as_float(u);
}

// decode fp4 e2m1 code (4 bits incl. sign) -> float {0,.5,1,1.5,2,3,4,6}*sign
__device__ inline float fp4_dec(u32 c) {
    u32 e = (c >> 1) & 3u;
    float m = (float)(c & 1u);
    float v = e ? (2.0f + m) * (float)(1u << e) * 0.25f : 0.5f * m;
    return (c & 8u) ? -v : v;
}

// reference fp4_121_positive with jnp.round == RNE == rintf
__device__ inline float fp4_round_mag(float a) {
    if (a < 2.0f) return rintf(2.0f * a) * 0.5f;
    if (a < 4.0f) return rintf(a);
    return 2.0f * rintf(a * 0.5f);
}

__device__ inline float pts_from_amax(float amax) {
    // clip(amax / 448, 2^-6, 448); true IEEE division to match reference
    return fminf(fmaxf(amax / 448.0f, 0.015625f), 448.0f);
}

// ---- grid sync (hand-rolled; all 256 blocks co-resident: 128KiB LDS ->
// 1 block/CU on 256 CUs). Counter zeroed by hipMemsetAsync each launch.

__device__ inline void grid_sync(u32* cnt, u32 target) {
    __syncthreads();
    __threadfence();                               // release prior writes (device scope)
    if (threadIdx.x == 0) {
        __hip_atomic_fetch_add(cnt, 1u, __ATOMIC_RELEASE, __HIP_MEMORY_SCOPE_AGENT);
        while (__hip_atomic_load(cnt, __ATOMIC_ACQUIRE, __HIP_MEMORY_SCOPE_AGENT) < target)
            __builtin_amdgcn_s_sleep(2);
    }
    __syncthreads();
    __threadfence();                               // acquire side for all waves
}

// ---- the mega kernel -----------------------------------------------------
// Phase A: amax partials + weight dequant (independent work rides along)
// sync -> Phase B: every block reduces partials; QDQ x -> bf16 A
// sync -> Phase C: 256x256-tile GEMM, 2 tiles per block (6-phase counted-
//                  vmcnt schedule, T2 swizzle, verified R2/R3)

#define GLDS(g, l)                                                              \
    __builtin_amdgcn_global_load_lds(                                           \
        (const __attribute__((address_space(1))) unsigned int*)(g),             \
        (__attribute__((address_space(3))) unsigned int*)(l), 16, 0, 0)

__global__ __launch_bounds__(512, 2) void mega(
    const float4* __restrict__ x, const int* __restrict__ wp,
    const float* __restrict__ wsc, const float* __restrict__ wgs,
    uint2* __restrict__ aq, u16* __restrict__ wq, float* __restrict__ C,
    u32* __restrict__ cnt, float* __restrict__ part)
{
    __shared__ u16 sh[2][2][2][8192];   // gemm tiles (128 KiB)
    __shared__ float sm8[8];            // small reduce scratch

    const int tid = threadIdx.x;
    const int w = tid >> 6, lane = tid & 63;
    const int gtid = blockIdx.x * 512 + tid;       // 0..131071

    // ================= Phase A: amax partials + weight dequant ===========
    {
        float mx = 0.0f;
#pragma unroll 4
        for (int it = 0; it < 64; ++it) {           // 8.4M float4 / 131072
            float4 v = x[gtid + it * 131072];
            mx = fmaxf(mx, fmaxf(fmaxf(fabsf(v.x), fabsf(v.y)),
                                 fmaxf(fabsf(v.z), fabsf(v.w))));
        }
        // weight dequant: N*K/2 = 2,097,152 bytes-of-2-codes, 16 per thread
        float ginv = wgs[0];
#pragma unroll 4
        for (int g = 0; g < 16; ++g) {
            int i = gtid + g * 131072;
            int n = i >> 10;                        // Khalf = 1024
            int kb = i & 1023;
            u32 byte = (u32)wp[i] & 0xFFu;
            float scale = wsc[(size_t)n * (K / 16) + (kb >> 3)] / ginv;
            float lo = fp4_dec(byte & 0xFu) * scale;
            float hi = fp4_dec((byte >> 4) & 0xFu) * scale;
            ((u32*)wq)[i] = (u32)f32_to_bf16(lo) | ((u32)f32_to_bf16(hi) << 16);
        }
#pragma unroll
        for (int off = 32; off > 0; off >>= 1)
            mx = fmaxf(mx, __shfl_down(mx, off));
        if (lane == 0) sm8[w] = mx;
        __syncthreads();
        if (tid == 0) {
            float m = sm8[0];
#pragma unroll
            for (int i = 1; i < 8; i++) m = fmaxf(m, sm8[i]);
            __hip_atomic_store(&part[blockIdx.x], m, __ATOMIC_RELAXED,
                               __HIP_MEMORY_SCOPE_AGENT);
        }
    }

    grid_sync(cnt, 256);

    // ================= Phase B: reduce partials; QDQ x -> aq =============
    float pts;
    {
        float m = (tid < 256)
            ? __hip_atomic_load(&part[tid], __ATOMIC_RELAXED, __HIP_MEMORY_SCOPE_AGENT)
            : 0.0f;
#pragma unroll
        for (int off = 32; off > 0; off >>= 1)
            m = fmaxf(m, __shfl_down(m, off));
        if (lane == 0) sm8[w] = m;
        __syncthreads();
        float amax = sm8[0];
#pragma unroll
        for (int i = 1; i < 8; i++) amax = fmaxf(amax, sm8[i]);
        pts = pts_from_amax(amax);

#pragma unroll 2
        for (int it = 0; it < 64; ++it) {
            int idx = gtid + it * 131072;           // consecutive lanes -> consecutive f4
            float4 v = x[idx];                      // L3-warm from phase A

            float bm = fmaxf(fmaxf(fabsf(v.x), fabsf(v.y)),
                             fmaxf(fabsf(v.z), fabsf(v.w)));
            bm = fmaxf(bm, __shfl_xor(bm, 1));
            bm = fmaxf(bm, __shfl_xor(bm, 2));      // 4-lane group = one 16-block

            float bs = bm / 6.0f;
            float sbs = e4m3_rne(fminf(fmaxf(bs / pts, 0.015625f), 448.0f));
            float ts = pts * sbs;

            float vf[4] = {v.x, v.y, v.z, v.w};
            u16 o[4];
#pragma unroll
            for (int i = 0; i < 4; i++) {
                float s = vf[i] / ts;               // IEEE div, matches ref
                s = fminf(fmaxf(s, -6.0f), 6.0f);
                float lp = copysignf(fp4_round_mag(fabsf(s)), s);
                o[i] = f32_to_bf16(lp * sbs);       // exact product
            }
            aq[idx] = *(const uint2*)o;
        }
    }

    grid_sync(cnt, 512);

    // ================= Phase C: GEMM, 2 tiles per block ==================
    const u16* A = (const u16*)aq;
    const u16* B = wq;

    // XCD swizzle (256 blocks, bijective): each XCD owns 4 bm x 8 bn
    const int id = blockIdx.x;
    const int xcd = id & 7;
    const int local = id >> 3;                     // 0..31
    const int bmbase = xcd * 4 + (local >> 3);     // 0..31 ; pass1 adds 32
    const int bn = local & 7;                      // 0..7

    const int wm = w >> 2, wn = w & 3;             // 2x4 wave grid
    const int r16 = lane & 15, q = lane >> 4;

    floatx4 acc[8][4] = {};

    // swizzled fragment read offsets (u16 units)
    const int swz = (r16 & 7) << 4;
    const int aoff0 = r16 * 64 + (((q * 16) ^ swz) >> 1);
    const int aoff1 = r16 * 64 + (((64 + q * 16) ^ swz) >> 1);

    // staging source geometry (pre-swizzled per lane)
    const int srow8 = lane >> 3;                   // 0..7
    const int scol = ((lane & 7) ^ srow8) * 8;     // u16 units
    const u16* gA[2];
    const u16* gB[2];
    gB[0] = B + (size_t)(bn * 256 + (w * 2 + 0) * 8 + srow8) * K + scol;
    gB[1] = B + (size_t)(bn * 256 + (w * 2 + 1) * 8 + srow8) * K + scol;

#define STG(buf, mat, half, ktc) do {                                           \
        const u16* _s0 = ((mat) ? gB[0] : gA[0]) + (size_t)(half) * 128 * K + (ktc); \
        const u16* _s1 = ((mat) ? gB[1] : gA[1]) + (size_t)(half) * 128 * K + (ktc); \
        GLDS(_s0, &sh[buf][mat][half][w * 1024]);                               \
        GLDS(_s1, &sh[buf][mat][half][w * 1024 + 512]);                         \
    } while (0)

    short8 aF[4][2], bF[4][2];

#define RD_A(buf, Qa) do {                                                      \
        const u16* _ar = &sh[buf][0][wm][(Qa) * 4096];                          \
        _Pragma("unroll") for (int _i = 0; _i < 4; _i++) {                      \
            aF[_i][0] = *(const short8*)(_ar + _i * 1024 + aoff0);              \
            aF[_i][1] = *(const short8*)(_ar + _i * 1024 + aoff1); }            \
    } while (0)

#define RD_B(buf, Qb) do {                                                      \
        const u16* _br = &sh[buf][1][wn >> 1][(wn & 1) * 4096 + (Qb) * 2048];   \
        _Pragma("unroll") for (int _j = 0; _j < 2; _j++) {                      \
            bF[(Qb) * 2 + _j][0] = *(const short8*)(_br + _j * 1024 + aoff0);   \
            bF[(Qb) * 2 + _j][1] = *(const short8*)(_br + _j * 1024 + aoff1); } \
    } while (0)

#define MMAQ(Qa, Qb)                                                            \
        _Pragma("unroll") for (int _i = 0; _i < 4; _i++)                        \
        _Pragma("unroll") for (int _j = 0; _j < 2; _j++)                        \
        _Pragma("unroll") for (int _k = 0; _k < 2; _k++)                        \
            acc[(Qa) * 4 + _i][(Qb) * 2 + _j] =                                 \
                __builtin_amdgcn_mfma_f32_16x16x32_bf16(                        \
                    aF[_i][_k], bF[(Qb) * 2 + _j][_k],                          \
                    acc[(Qa) * 4 + _i][(Qb) * 2 + _j], 0, 0, 0)

#define BAR do { __builtin_amdgcn_sched_barrier(0);                             \
                 __builtin_amdgcn_s_barrier();                                  \
                 __builtin_amdgcn_sched_barrier(0); } while (0)
#define PRIO1 __builtin_amdgcn_s_setprio(1)
#define PRIO0 do { __builtin_amdgcn_s_setprio(0);                               \
                   __builtin_amdgcn_sched_barrier(0); } while (0)
#define ENDPH do { __builtin_amdgcn_s_barrier();                                \
                   __builtin_amdgcn_sched_barrier(0); } while (0)
#define CHK4 do { asm volatile("s_waitcnt vmcnt(4)" ::: "memory");              \
                  __builtin_amdgcn_sched_barrier(0); } while (0)

#define CWRITE(bmv) do {                                                        \
        float* Cb = C + (size_t)((bmv) * 256 + wm * 128 + q * 4) * N            \
                      + bn * 256 + wn * 64 + r16;                               \
        _Pragma("unroll") for (int _i = 0; _i < 8; _i++)                        \
        _Pragma("unroll") for (int _j = 0; _j < 4; _j++)                        \
        _Pragma("unroll") for (int _t = 0; _t < 4; _t++)                        \
            Cb[(size_t)(_i * 16 + _t) * N + _j * 16] = pts * acc[_i][_j][_t];   \
    } while (0)

#pragma unroll 1
    for (int pass = 0; pass < 2; ++pass) {
        const int bm = bmbase + pass * 32;
        gA[0] = A + (size_t)(bm * 256 + (w * 2 + 0) * 8 + srow8) * K + scol;
        gA[1] = A + (size_t)(bm * 256 + (w * 2 + 1) * 8 + srow8) * K + scol;

        // prologue: X(kt0) fully + Y(kt1) B halves
        STG(0, 0, 0, 0); STG(0, 0, 1, 0);        // X.A0 X.A1
        STG(0, 1, 0, 0); STG(0, 1, 1, 0);        // X.B0 X.B1
        STG(1, 1, 0, 64); STG(1, 1, 1, 64);      // Y.B0 Y.B1
        CHK4;                                     // X landed; Y.B may fly
        __builtin_amdgcn_s_barrier();

        if (pass) {
            // pass0 C-write overlaps pass1's in-flight Y.B loads; the 128
            // stores drain at pass1's first in-loop CHK4 (bounded stall).
            CWRITE(bmbase);
#pragma unroll
            for (int i = 0; i < 8; i++)
#pragma unroll
                for (int j = 0; j < 4; j++)
                    acc[i][j] = (floatx4){0.f, 0.f, 0.f, 0.f};
        }

#pragma unroll 1
        for (int it = 0; it < K / 128; ++it) {
            const int ktY  = (2 * it + 1) * 64;
            const int kx2  = 2 * it + 2, ky2 = 2 * it + 3;
            const int ktX2 = (kx2 <= 31 ? kx2 : 31) * 64;   // clamp: last-iter
            const int ktY2 = (ky2 <= 31 ? ky2 : 31) * 64;   // stages are dummies

            // ---- X tile (buf 0) ----
            RD_A(0, 0); RD_B(0, 0); STG(1, 0, 0, ktY);
            BAR; PRIO1; MMAQ(0, 0); PRIO0; ENDPH;
            RD_B(0, 1); STG(1, 0, 1, ktY);
            BAR; PRIO1; MMAQ(0, 1); PRIO0; ENDPH;
            RD_A(0, 1); STG(0, 1, 0, ktX2); STG(0, 1, 1, ktX2);
            BAR; PRIO1; MMAQ(1, 1); MMAQ(1, 0); PRIO0; CHK4; ENDPH;
            // ---- Y tile (buf 1) ----
            RD_A(1, 0); RD_B(1, 0); STG(0, 0, 0, ktX2);
            BAR; PRIO1; MMAQ(0, 0); PRIO0; ENDPH;
            RD_B(1, 1); STG(0, 0, 1, ktX2);
            BAR; PRIO1; MMAQ(0, 1); PRIO0; ENDPH;
            RD_A(1, 1); STG(1, 1, 0, ktY2); STG(1, 1, 1, ktY2);
            BAR; PRIO1; MMAQ(1, 1); MMAQ(1, 0); PRIO0; CHK4; ENDPH;
        }

        // drain stray (clamped) stages before LDS reuse / epilogue
        asm volatile("s_waitcnt vmcnt(0)" ::: "memory");
    }

    CWRITE(bmbase + 32);
}

// ---- launch --------------------------------------------------------------

extern "C" void kernel_launch(void* const* d_in, const int* in_sizes, int n_in,
                              void* d_out, int out_size, void* d_ws, size_t ws_size,
                              hipStream_t stream) {
    const float* x   = (const float*)d_in[0];
    const int*   wp  = (const int*)d_in[1];
    const float* wsc = (const float*)d_in[2];
    const float* wgs = (const float*)d_in[3];
    float* out = (float*)d_out;

    // workspace layout:
    //   +0      : grid-sync counter (u32, zeroed per launch)
    //   +64     : 256 float partial maxima
    //   +16384  : A bf16 [M*K]
    //   then    : B bf16 [N*K]
    u32*   cnt  = (u32*)d_ws;
    float* part = (float*)((char*)d_ws + 64);
    u16*   aq   = (u16*)((char*)d_ws + 16384);
    u16*   wq   = aq + (size_t)M * K;

    hipMemsetAsync(d_ws, 0, 64, stream);
    mega<<<256, 512, 0, stream>>>((const float4*)x, wp, wsc, wgs,
                                  (uint2*)aq, wq, out, cnt, part);
}

// Round 5
// 491.558 us; speedup vs baseline: 1.3289x; 1.3289x over previous
//
#include <hip/hip_runtime.h>

typedef unsigned short u16;
typedef unsigned int u32;
typedef __attribute__((ext_vector_type(8))) short short8;
typedef __attribute__((ext_vector_type(4))) float floatx4;

static constexpr int M = 16384, N = 2048, K = 2048;

// ---- helpers -------------------------------------------------------------

__device__ inline u16 f32_to_bf16(float x) {
    u32 u = __float_as_uint(x);
    u += 0x7FFFu + ((u >> 16) & 1u);
    return (u16)(u >> 16);
}

// RNE round to e4m3 grid; valid for x in [2^-6, 448] (normal e4m3 range,
// guaranteed by the preceding clip). 3 mantissa bits -> round at fp32 bit 20.
__device__ inline float e4m3_rne(float x) {
    u32 u = __float_as_uint(x);
    u += 0x7FFFFu + ((u >> 20) & 1u);
    u &= 0xFFF00000u;
    return __uint_as_float(u);
}

// decode fp4 e2m1 code (4 bits incl. sign) -> float {0,.5,1,1.5,2,3,4,6}*sign
__device__ inline float fp4_dec(u32 c) {
    u32 e = (c >> 1) & 3u;
    float m = (float)(c & 1u);
    float v = e ? (2.0f + m) * (float)(1u << e) * 0.25f : 0.5f * m;
    return (c & 8u) ? -v : v;
}

// reference fp4_121_positive with jnp.round == RNE == rintf
__device__ inline float fp4_round_mag(float a) {
    if (a < 2.0f) return rintf(2.0f * a) * 0.5f;
    if (a < 4.0f) return rintf(a);
    return 2.0f * rintf(a * 0.5f);
}

__device__ inline float pts_from_amax(float amax) {
    // clip(amax / 448, 2^-6, 448); true IEEE division to match reference
    return fminf(fmaxf(amax / 448.0f, 0.015625f), 448.0f);
}

// ---- kernel 1: partial amax + weight dequant + last-block finalize ------
// Weight dequant is independent of amax and rides along (its 16 MB of
// traffic overlaps the 134 MB amax stream). The LAST block to finish
// reduces the 2048 partials and writes amax_bits -- no separate fin
// kernel. Device-scope atomics + threadfence per G16.

__global__ __launch_bounds__(256) void amax_part(
    const float4* __restrict__ x, float* __restrict__ part,
    const int* __restrict__ wp, const float* __restrict__ wsc,
    const float* __restrict__ wgs, u16* __restrict__ wq,
    u32* __restrict__ cnt, u32* __restrict__ amax_bits) {
    int idx = blockIdx.x * blockDim.x + threadIdx.x;   // grid 2048x256
    float m = 0.0f;
#pragma unroll 4
    for (int it = 0; it < 16; ++it) {                   // 8.4M float4
        float4 v = x[idx + it * 524288];
        m = fmaxf(m, fmaxf(fmaxf(fabsf(v.x), fabsf(v.y)),
                           fmaxf(fabsf(v.z), fabsf(v.w))));
    }

    // weight dequant: N*K/2 = 2,097,152 packed bytes, 4 per thread
    float ginv = wgs[0];
#pragma unroll
    for (int g = 0; g < 4; g++) {
        int i = idx + g * 524288;
        int n = i >> 10;                                // Khalf = 1024
        int kb = i & 1023;
        u32 byte = (u32)wp[i] & 0xFFu;
        float scale = wsc[(size_t)n * (K / 16) + (kb >> 3)] / ginv;
        float lo = fp4_dec(byte & 0xFu) * scale;
        float hi = fp4_dec((byte >> 4) & 0xFu) * scale;
        ((u32*)wq)[i] = (u32)f32_to_bf16(lo) | ((u32)f32_to_bf16(hi) << 16);
    }

#pragma unroll
    for (int off = 32; off > 0; off >>= 1)
        m = fmaxf(m, __shfl_down(m, off));
    __shared__ float sm[4];
    __shared__ bool last;
    if ((threadIdx.x & 63) == 0) sm[threadIdx.x >> 6] = m;
    __syncthreads();
    if (threadIdx.x == 0) {
        part[blockIdx.x] = fmaxf(fmaxf(sm[0], sm[1]), fmaxf(sm[2], sm[3]));
        __threadfence();                                // release part[]
        u32 d = __hip_atomic_fetch_add(cnt, 1u, __ATOMIC_ACQ_REL,
                                       __HIP_MEMORY_SCOPE_AGENT);
        last = (d == 2047u);
    }
    __syncthreads();
    if (last) {
        __threadfence();                                // acquire all part[]
        int t = threadIdx.x;
        float r = 0.0f;
#pragma unroll
        for (int i = 0; i < 8; i++) r = fmaxf(r, part[t + i * 256]);
#pragma unroll
        for (int off = 32; off > 0; off >>= 1)
            r = fmaxf(r, __shfl_down(r, off));
        if ((t & 63) == 0) sm[t >> 6] = r;
        __syncthreads();
        if (t == 0)
            *amax_bits = __float_as_uint(
                fmaxf(fmaxf(sm[0], sm[1]), fmaxf(sm[2], sm[3])));
    }
}

// ---- kernel 2: QDQ x -> bf16 A = lp * sbs (exact in bf16) ---------------
// Grid-stride (G11): 2048 blocks, 16 float4/thread for load ILP.

__global__ __launch_bounds__(256) void prep(
    const float4* __restrict__ x, uint2* __restrict__ aq,
    const u32* __restrict__ amax_bits) {
    int idx0 = blockIdx.x * blockDim.x + threadIdx.x;
    float pts = pts_from_amax(__uint_as_float(*amax_bits));

#pragma unroll 4
    for (int it = 0; it < 16; ++it) {
        int idx = idx0 + it * 524288;
        float4 v = x[idx];                              // L3-warm from amax

        float bm = fmaxf(fmaxf(fabsf(v.x), fabsf(v.y)),
                         fmaxf(fabsf(v.z), fabsf(v.w)));
        bm = fmaxf(bm, __shfl_xor(bm, 1));
        bm = fmaxf(bm, __shfl_xor(bm, 2));              // 4-lane group = 16-block

        float bs = bm / 6.0f;
        float sbs = e4m3_rne(fminf(fmaxf(bs / pts, 0.015625f), 448.0f));
        float ts = pts * sbs;

        float vf[4] = {v.x, v.y, v.z, v.w};
        u16 o[4];
#pragma unroll
        for (int i = 0; i < 4; i++) {
            float s = vf[i] / ts;                       // IEEE div, matches ref
            s = fminf(fmaxf(s, -6.0f), 6.0f);
            float lp = copysignf(fp4_round_mag(fabsf(s)), s);
            o[i] = f32_to_bf16(lp * sbs);               // exact product
        }
        aq[idx] = *(const uint2*)o;
    }
}

// ---- kernel 3: bf16 GEMM, 256x256 tile, 6-phase counted-vmcnt schedule --
//
// m201-template port (verified R2/R3, absmax 0.0). New in R5: LDS-staged
// coalesced C-write. After the K-loop, one vmcnt(0)+barrier guarantees ALL
// waves' in-flight global_load_lds have landed (wave 7's C-stage region
// overlaps wave 6's buf0-A staging dest -- the barrier closes that race);
// then each wave transposes acc through its private 4 KiB LDS region and
// stores float4s: 16 consecutive lanes cover 256 B contiguous per C row
// (vs 64 B segments before), 32 dwordx4 vs 128 dword stores.

#define GLDS(g, l)                                                              \
    __builtin_amdgcn_global_load_lds(                                           \
        (const __attribute__((address_space(1))) unsigned int*)(g),             \
        (__attribute__((address_space(3))) unsigned int*)(l), 16, 0, 0)

__global__ __launch_bounds__(512, 2) void gemm_bt(
    const u16* __restrict__ A, const u16* __restrict__ B,
    float* __restrict__ C, const u32* __restrict__ amax_bits)
{
    // [buf][mat A=0/B=1][half][128 rows * 64 cols] bf16, 16 KiB per half
    __shared__ u16 sh[2][2][2][8192];

    const int tid = threadIdx.x;
    const int w = tid >> 6, lane = tid & 63;

    // XCD swizzle (512 blocks, 512%8==0 -> bijective):
    // each XCD owns 8 bm rows x 8 bn -> A panel resident in one L2.
    const int id = blockIdx.x;
    const int xcd = id & 7;
    const int local = id >> 3;                   // 0..63 per XCD
    const int bm = xcd * 8 + (local >> 3);       // 0..63  (M/256)
    const int bn = local & 7;                    // 0..7   (N/256)

    const int wm = w >> 2, wn = w & 3;           // 2x4 wave grid
    const int r16 = lane & 15, q = lane >> 4;

    floatx4 acc[8][4] = {};

    // ---- swizzled fragment read offsets (u16 units) ----
    const int swz = (r16 & 7) << 4;                          // byte XOR value
    const int aoff0 = r16 * 64 + (((q * 16) ^ swz) >> 1);          // ks=0
    const int aoff1 = r16 * 64 + (((64 + q * 16) ^ swz) >> 1);     // ks=1

    // ---- staging source pointers (pre-swizzled per lane) ----
    const int srow8 = lane >> 3;                             // 0..7
    const int scol = ((lane & 7) ^ srow8) * 8;               // u16 units
    const u16* gA[2], * gB[2];
    gA[0] = A + (size_t)(bm * 256 + (w * 2 + 0) * 8 + srow8) * K + scol;
    gA[1] = A + (size_t)(bm * 256 + (w * 2 + 1) * 8 + srow8) * K + scol;
    gB[0] = B + (size_t)(bn * 256 + (w * 2 + 0) * 8 + srow8) * K + scol;
    gB[1] = B + (size_t)(bn * 256 + (w * 2 + 1) * 8 + srow8) * K + scol;

#define STG(buf, mat, half, ktc) do {                                           \
        const u16* _s0 = ((mat) ? gB[0] : gA[0]) + (size_t)(half) * 128 * K + (ktc); \
        const u16* _s1 = ((mat) ? gB[1] : gA[1]) + (size_t)(half) * 128 * K + (ktc); \
        GLDS(_s0, &sh[buf][mat][half][w * 1024]);                               \
        GLDS(_s1, &sh[buf][mat][half][w * 1024 + 512]);                         \
    } while (0)

    short8 aF[4][2], bF[4][2];

#define RD_A(buf, Qa) do {                                                      \
        const u16* _ar = &sh[buf][0][wm][(Qa) * 4096];                          \
        _Pragma("unroll") for (int _i = 0; _i < 4; _i++) {                      \
            aF[_i][0] = *(const short8*)(_ar + _i * 1024 + aoff0);              \
            aF[_i][1] = *(const short8*)(_ar + _i * 1024 + aoff1); }            \
    } while (0)

#define RD_B(buf, Qb) do {                                                      \
        const u16* _br = &sh[buf][1][wn >> 1][(wn & 1) * 4096 + (Qb) * 2048];   \
        _Pragma("unroll") for (int _j = 0; _j < 2; _j++) {                      \
            bF[(Qb) * 2 + _j][0] = *(const short8*)(_br + _j * 1024 + aoff0);   \
            bF[(Qb) * 2 + _j][1] = *(const short8*)(_br + _j * 1024 + aoff1); } \
    } while (0)

    // 16 MFMAs of one quadrant; registers only, no sync
#define MMAQ(Qa, Qb)                                                            \
        _Pragma("unroll") for (int _i = 0; _i < 4; _i++)                        \
        _Pragma("unroll") for (int _j = 0; _j < 2; _j++)                        \
        _Pragma("unroll") for (int _k = 0; _k < 2; _k++)                        \
            acc[(Qa) * 4 + _i][(Qb) * 2 + _j] =                                 \
                __builtin_amdgcn_mfma_f32_16x16x32_bf16(                        \
                    aF[_i][_k], bF[(Qb) * 2 + _j][_k],                          \
                    acc[(Qa) * 4 + _i][(Qb) * 2 + _j], 0, 0, 0)

#define BAR do { __builtin_amdgcn_sched_barrier(0);                             \
                 __builtin_amdgcn_s_barrier();                                  \
                 __builtin_amdgcn_sched_barrier(0); } while (0)
#define PRIO1 __builtin_amdgcn_s_setprio(1)
#define PRIO0 do { __builtin_amdgcn_s_setprio(0);                               \
                   __builtin_amdgcn_sched_barrier(0); } while (0)
#define ENDPH do { __builtin_amdgcn_s_barrier();                                \
                   __builtin_amdgcn_sched_barrier(0); } while (0)
#define CHK4 do { asm volatile("s_waitcnt vmcnt(4)" ::: "memory");              \
                  __builtin_amdgcn_sched_barrier(0); } while (0)

    // ---- prologue: X(kt0) fully + Y(kt1) B halves ----
    STG(0, 0, 0, 0); STG(0, 0, 1, 0);        // X.A0 X.A1
    STG(0, 1, 0, 0); STG(0, 1, 1, 0);        // X.B0 X.B1
    STG(1, 1, 0, 64); STG(1, 1, 1, 64);      // Y.B0 Y.B1
    CHK4;                                     // X landed; Y.B may fly
    __builtin_amdgcn_s_barrier();

#pragma unroll 1
    for (int it = 0; it < K / 128; ++it) {
        const int ktY  = (2 * it + 1) * 64;
        const int kx2  = 2 * it + 2, ky2 = 2 * it + 3;
        const int ktX2 = (kx2 <= 31 ? kx2 : 31) * 64;   // clamp: last-iter
        const int ktY2 = (ky2 <= 31 ? ky2 : 31) * 64;   // stages are dummies

        // ---- X tile (buf 0) ----
        RD_A(0, 0); RD_B(0, 0); STG(1, 0, 0, ktY);
        BAR; PRIO1; MMAQ(0, 0); PRIO0; ENDPH;
        RD_B(0, 1); STG(1, 0, 1, ktY);
        BAR; PRIO1; MMAQ(0, 1); PRIO0; ENDPH;
        RD_A(0, 1); STG(0, 1, 0, ktX2); STG(0, 1, 1, ktX2);
        BAR; PRIO1; MMAQ(1, 1); MMAQ(1, 0); PRIO0; CHK4; ENDPH;
        // ---- Y tile (buf 1) ----
        RD_A(1, 0); RD_B(1, 0); STG(0, 0, 0, ktX2);
        BAR; PRIO1; MMAQ(0, 0); PRIO0; ENDPH;
        RD_B(1, 1); STG(0, 0, 1, ktX2);
        BAR; PRIO1; MMAQ(0, 1); PRIO0; ENDPH;
        RD_A(1, 1); STG(1, 1, 0, ktY2); STG(1, 1, 1, ktY2);
        BAR; PRIO1; MMAQ(1, 1); MMAQ(1, 0); PRIO0; CHK4; ENDPH;
    }

    // ALL waves' in-flight global_load_lds must land before LDS is reused
    // for C staging (wave w's stage region overlaps wave w-1's buf0-A dest).
    asm volatile("s_waitcnt vmcnt(0)" ::: "memory");
    __builtin_amdgcn_s_barrier();
    __builtin_amdgcn_sched_barrier(0);

    float pts = pts_from_amax(__uint_as_float(*amax_bits));

    // ---- LDS-staged coalesced C-write ----
    // Per wave: private 4 KiB region; per i-block (16 rows x 64 cols f32):
    // scatter acc (col=lane-fragment layout) -> LDS, read back float4,
    // store 256 B contiguous per row (16 lanes x 16 B).
    float* stage = (float*)&sh[0][0][0][0] + w * 1024;
    const int erow = lane >> 4;              // 0..3 (row within 4-row group)
    const int ecol = lane & 15;              // 0..15 (16 B chunk)
    float* Cb = C + (size_t)(bm * 256 + wm * 128) * N + bn * 256 + wn * 64;
#pragma unroll
    for (int i = 0; i < 8; i++) {
        // C/D layout (verified m89/m91): col = lane&15, row = (lane>>4)*4+reg
#pragma unroll
        for (int j = 0; j < 4; j++)
#pragma unroll
            for (int t = 0; t < 4; t++)
                stage[(q * 4 + t) * 64 + j * 16 + r16] = pts * acc[i][j][t];
        asm volatile("s_waitcnt lgkmcnt(0)" ::: "memory");  // writes landed
        __builtin_amdgcn_sched_barrier(0);
#pragma unroll
        for (int k4 = 0; k4 < 4; k4++) {
            float4 vv = *(const float4*)&stage[(k4 * 4 + erow) * 64 + ecol * 4];
            *(float4*)&Cb[(size_t)(i * 16 + k4 * 4 + erow) * N + ecol * 4] = vv;
        }
        asm volatile("s_waitcnt lgkmcnt(0)" ::: "memory");  // reads done (WAR)
        __builtin_amdgcn_sched_barrier(0);
    }
}

// ---- launch --------------------------------------------------------------

extern "C" void kernel_launch(void* const* d_in, const int* in_sizes, int n_in,
                              void* d_out, int out_size, void* d_ws, size_t ws_size,
                              hipStream_t stream) {
    const float* x   = (const float*)d_in[0];
    const int*   wp  = (const int*)d_in[1];
    const float* wsc = (const float*)d_in[2];
    const float* wgs = (const float*)d_in[3];
    float* out = (float*)d_out;

    // workspace layout:
    //   +0      : done-counter (u32, zeroed per launch)
    //   +4      : amax bits (u32, written by amax_part's last block)
    //   +64     : 2048 float partial maxima
    //   +16384  : A bf16 [M*K]
    //   then    : B bf16 [N*K]
    u32*   cnt       = (u32*)d_ws;
    u32*   amax_bits = (u32*)((char*)d_ws + 4);
    float* part      = (float*)((char*)d_ws + 64);
    u16*   aq        = (u16*)((char*)d_ws + 16384);
    u16*   wq        = aq + (size_t)M * K;

    hipMemsetAsync(d_ws, 0, 64, stream);
    amax_part<<<2048, 256, 0, stream>>>((const float4*)x, part,
                                        wp, wsc, wgs, wq, cnt, amax_bits);
    prep<<<2048, 256, 0, stream>>>((const float4*)x, (uint2*)aq, amax_bits);
    gemm_bt<<<512, 512, 0, stream>>>(aq, wq, out, amax_bits);
}

// Round 6
// 374.944 us; speedup vs baseline: 1.7422x; 1.3110x over previous
//
#include <hip/hip_runtime.h>

typedef unsigned short u16;
typedef unsigned int u32;
typedef __attribute__((ext_vector_type(8))) short short8;
typedef __attribute__((ext_vector_type(4))) float floatx4;

static constexpr int M = 16384, N = 2048, K = 2048;

// ---- helpers -------------------------------------------------------------

__device__ inline u16 f32_to_bf16(float x) {
    u32 u = __float_as_uint(x);
    u += 0x7FFFu + ((u >> 16) & 1u);
    return (u16)(u >> 16);
}

// RNE round to e4m3 grid; valid for x in [2^-6, 448] (normal e4m3 range,
// guaranteed by the preceding clip). 3 mantissa bits -> round at fp32 bit 20.
__device__ inline float e4m3_rne(float x) {
    u32 u = __float_as_uint(x);
    u += 0x7FFFFu + ((u >> 20) & 1u);
    u &= 0xFFF00000u;
    return __uint_as_float(u);
}

// decode fp4 e2m1 code (4 bits incl. sign) -> float {0,.5,1,1.5,2,3,4,6}*sign
__device__ inline float fp4_dec(u32 c) {
    u32 e = (c >> 1) & 3u;
    float m = (float)(c & 1u);
    float v = e ? (2.0f + m) * (float)(1u << e) * 0.25f : 0.5f * m;
    return (c & 8u) ? -v : v;
}

// reference fp4_121_positive with jnp.round == RNE == rintf
__device__ inline float fp4_round_mag(float a) {
    if (a < 2.0f) return rintf(2.0f * a) * 0.5f;
    if (a < 4.0f) return rintf(a);
    return 2.0f * rintf(a * 0.5f);
}

__device__ inline float pts_from_amax(float amax) {
    // clip(amax / 448, 2^-6, 448); true IEEE division to match reference
    return fminf(fmaxf(amax / 448.0f, 0.015625f), 448.0f);
}

// ---- kernel 1: partial amax + weight dequant ----------------------------
// Weight dequant is independent of amax and rides along (its 16 MB of
// traffic overlaps the 134 MB amax stream). NO device-scope fences here:
// R5 measured the last-block-finalize pattern (threadfence + atomic per
// block) at +100 us -- L2 writebacks mid-stream. The kernel boundary
// before amax_fin is the cheap release.

__global__ __launch_bounds__(256) void amax_part(
    const float4* __restrict__ x, float* __restrict__ part,
    const int* __restrict__ wp, const float* __restrict__ wsc,
    const float* __restrict__ wgs, u16* __restrict__ wq) {
    int idx = blockIdx.x * blockDim.x + threadIdx.x;   // grid 2048x256
    float m = 0.0f;
#pragma unroll 4
    for (int it = 0; it < 16; ++it) {                   // 8.4M float4
        float4 v = x[idx + it * 524288];
        m = fmaxf(m, fmaxf(fmaxf(fabsf(v.x), fabsf(v.y)),
                           fmaxf(fabsf(v.z), fabsf(v.w))));
    }

    // weight dequant: N*K/2 = 2,097,152 packed bytes, 4 per thread
    float ginv = wgs[0];
#pragma unroll
    for (int g = 0; g < 4; g++) {
        int i = idx + g * 524288;
        int n = i >> 10;                                // Khalf = 1024
        int kb = i & 1023;
        u32 byte = (u32)wp[i] & 0xFFu;
        float scale = wsc[(size_t)n * (K / 16) + (kb >> 3)] / ginv;
        float lo = fp4_dec(byte & 0xFu) * scale;
        float hi = fp4_dec((byte >> 4) & 0xFu) * scale;
        ((u32*)wq)[i] = (u32)f32_to_bf16(lo) | ((u32)f32_to_bf16(hi) << 16);
    }

#pragma unroll
    for (int off = 32; off > 0; off >>= 1)
        m = fmaxf(m, __shfl_down(m, off));
    __shared__ float sm[4];
    if ((threadIdx.x & 63) == 0) sm[threadIdx.x >> 6] = m;
    __syncthreads();
    if (threadIdx.x == 0)
        part[blockIdx.x] = fmaxf(fmaxf(sm[0], sm[1]), fmaxf(sm[2], sm[3]));
}

// ---- kernel 1b: finalize amax (1 block, 1024 threads, 2048 partials) ----

__global__ void amax_fin(const float* __restrict__ part, u32* __restrict__ out) {
    int t = threadIdx.x;
    float m = fmaxf(part[t], part[t + 1024]);
#pragma unroll
    for (int off = 32; off > 0; off >>= 1)
        m = fmaxf(m, __shfl_down(m, off));
    __shared__ float sm[16];
    if ((t & 63) == 0) sm[t >> 6] = m;
    __syncthreads();
    if (t < 16) {
        m = sm[t];
#pragma unroll
        for (int off = 8; off > 0; off >>= 1)
            m = fmaxf(m, __shfl_down(m, off));
        if (t == 0) *out = __float_as_uint(m);
    }
}

// ---- kernel 2: QDQ x -> bf16 A = lp * sbs (exact in bf16) ---------------
// Grid-stride (G11): 2048 blocks, 16 float4/thread for load ILP.

__global__ __launch_bounds__(256) void prep(
    const float4* __restrict__ x, uint2* __restrict__ aq,
    const u32* __restrict__ amax_bits) {
    int idx0 = blockIdx.x * blockDim.x + threadIdx.x;
    float pts = pts_from_amax(__uint_as_float(*amax_bits));

#pragma unroll 4
    for (int it = 0; it < 16; ++it) {
        int idx = idx0 + it * 524288;
        float4 v = x[idx];                              // L3-warm from amax

        float bm = fmaxf(fmaxf(fabsf(v.x), fabsf(v.y)),
                         fmaxf(fabsf(v.z), fabsf(v.w)));
        bm = fmaxf(bm, __shfl_xor(bm, 1));
        bm = fmaxf(bm, __shfl_xor(bm, 2));              // 4-lane group = 16-block

        float bs = bm / 6.0f;
        float sbs = e4m3_rne(fminf(fmaxf(bs / pts, 0.015625f), 448.0f));
        float ts = pts * sbs;

        float vf[4] = {v.x, v.y, v.z, v.w};
        u16 o[4];
#pragma unroll
        for (int i = 0; i < 4; i++) {
            float s = vf[i] / ts;                       // IEEE div, matches ref
            s = fminf(fmaxf(s, -6.0f), 6.0f);
            float lp = copysignf(fp4_round_mag(fabsf(s)), s);
            o[i] = f32_to_bf16(lp * sbs);               // exact product
        }
        aq[idx] = *(const uint2*)o;
    }
}

// ---- kernel 3: bf16 GEMM, 256x256 tile, 6-phase counted-vmcnt schedule --
//
// m201-template port (verified R2/R3, absmax 0.0) + LDS-staged coalesced
// C-write (R5). After the K-loop, one vmcnt(0)+barrier guarantees ALL
// waves' in-flight global_load_lds have landed (wave w's C-stage region
// overlaps wave w-1's buf0-A staging dest -- the barrier closes that race);
// then each wave transposes acc through its private 4 KiB LDS region and
// stores float4s: 16 consecutive lanes cover 256 B contiguous per C row.

#define GLDS(g, l)                                                              \
    __builtin_amdgcn_global_load_lds(                                           \
        (const __attribute__((address_space(1))) unsigned int*)(g),             \
        (__attribute__((address_space(3))) unsigned int*)(l), 16, 0, 0)

__global__ __launch_bounds__(512, 2) void gemm_bt(
    const u16* __restrict__ A, const u16* __restrict__ B,
    float* __restrict__ C, const u32* __restrict__ amax_bits)
{
    // [buf][mat A=0/B=1][half][128 rows * 64 cols] bf16, 16 KiB per half
    __shared__ u16 sh[2][2][2][8192];

    const int tid = threadIdx.x;
    const int w = tid >> 6, lane = tid & 63;

    // XCD swizzle (512 blocks, 512%8==0 -> bijective):
    // each XCD owns 8 bm rows x 8 bn -> A panel resident in one L2.
    const int id = blockIdx.x;
    const int xcd = id & 7;
    const int local = id >> 3;                   // 0..63 per XCD
    const int bm = xcd * 8 + (local >> 3);       // 0..63  (M/256)
    const int bn = local & 7;                    // 0..7   (N/256)

    const int wm = w >> 2, wn = w & 3;           // 2x4 wave grid
    const int r16 = lane & 15, q = lane >> 4;

    floatx4 acc[8][4] = {};

    // ---- swizzled fragment read offsets (u16 units) ----
    const int swz = (r16 & 7) << 4;                          // byte XOR value
    const int aoff0 = r16 * 64 + (((q * 16) ^ swz) >> 1);          // ks=0
    const int aoff1 = r16 * 64 + (((64 + q * 16) ^ swz) >> 1);     // ks=1

    // ---- staging source pointers (pre-swizzled per lane) ----
    const int srow8 = lane >> 3;                             // 0..7
    const int scol = ((lane & 7) ^ srow8) * 8;               // u16 units
    const u16* gA[2], * gB[2];
    gA[0] = A + (size_t)(bm * 256 + (w * 2 + 0) * 8 + srow8) * K + scol;
    gA[1] = A + (size_t)(bm * 256 + (w * 2 + 1) * 8 + srow8) * K + scol;
    gB[0] = B + (size_t)(bn * 256 + (w * 2 + 0) * 8 + srow8) * K + scol;
    gB[1] = B + (size_t)(bn * 256 + (w * 2 + 1) * 8 + srow8) * K + scol;

#define STG(buf, mat, half, ktc) do {                                           \
        const u16* _s0 = ((mat) ? gB[0] : gA[0]) + (size_t)(half) * 128 * K + (ktc); \
        const u16* _s1 = ((mat) ? gB[1] : gA[1]) + (size_t)(half) * 128 * K + (ktc); \
        GLDS(_s0, &sh[buf][mat][half][w * 1024]);                               \
        GLDS(_s1, &sh[buf][mat][half][w * 1024 + 512]);                         \
    } while (0)

    short8 aF[4][2], bF[4][2];

#define RD_A(buf, Qa) do {                                                      \
        const u16* _ar = &sh[buf][0][wm][(Qa) * 4096];                          \
        _Pragma("unroll") for (int _i = 0; _i < 4; _i++) {                      \
            aF[_i][0] = *(const short8*)(_ar + _i * 1024 + aoff0);              \
            aF[_i][1] = *(const short8*)(_ar + _i * 1024 + aoff1); }            \
    } while (0)

#define RD_B(buf, Qb) do {                                                      \
        const u16* _br = &sh[buf][1][wn >> 1][(wn & 1) * 4096 + (Qb) * 2048];   \
        _Pragma("unroll") for (int _j = 0; _j < 2; _j++) {                      \
            bF[(Qb) * 2 + _j][0] = *(const short8*)(_br + _j * 1024 + aoff0);   \
            bF[(Qb) * 2 + _j][1] = *(const short8*)(_br + _j * 1024 + aoff1); } \
    } while (0)

    // 16 MFMAs of one quadrant; registers only, no sync
#define MMAQ(Qa, Qb)                                                            \
        _Pragma("unroll") for (int _i = 0; _i < 4; _i++)                        \
        _Pragma("unroll") for (int _j = 0; _j < 2; _j++)                        \
        _Pragma("unroll") for (int _k = 0; _k < 2; _k++)                        \
            acc[(Qa) * 4 + _i][(Qb) * 2 + _j] =                                 \
                __builtin_amdgcn_mfma_f32_16x16x32_bf16(                        \
                    aF[_i][_k], bF[(Qb) * 2 + _j][_k],                          \
                    acc[(Qa) * 4 + _i][(Qb) * 2 + _j], 0, 0, 0)

#define BAR do { __builtin_amdgcn_sched_barrier(0);                             \
                 __builtin_amdgcn_s_barrier();                                  \
                 __builtin_amdgcn_sched_barrier(0); } while (0)
#define PRIO1 __builtin_amdgcn_s_setprio(1)
#define PRIO0 do { __builtin_amdgcn_s_setprio(0);                               \
                   __builtin_amdgcn_sched_barrier(0); } while (0)
#define ENDPH do { __builtin_amdgcn_s_barrier();                                \
                   __builtin_amdgcn_sched_barrier(0); } while (0)
#define CHK4 do { asm volatile("s_waitcnt vmcnt(4)" ::: "memory");              \
                  __builtin_amdgcn_sched_barrier(0); } while (0)

    // ---- prologue: X(kt0) fully + Y(kt1) B halves ----
    STG(0, 0, 0, 0); STG(0, 0, 1, 0);        // X.A0 X.A1
    STG(0, 1, 0, 0); STG(0, 1, 1, 0);        // X.B0 X.B1
    STG(1, 1, 0, 64); STG(1, 1, 1, 64);      // Y.B0 Y.B1
    CHK4;                                     // X landed; Y.B may fly
    __builtin_amdgcn_s_barrier();

#pragma unroll 1
    for (int it = 0; it < K / 128; ++it) {
        const int ktY  = (2 * it + 1) * 64;
        const int kx2  = 2 * it + 2, ky2 = 2 * it + 3;
        const int ktX2 = (kx2 <= 31 ? kx2 : 31) * 64;   // clamp: last-iter
        const int ktY2 = (ky2 <= 31 ? ky2 : 31) * 64;   // stages are dummies

        // ---- X tile (buf 0) ----
        RD_A(0, 0); RD_B(0, 0); STG(1, 0, 0, ktY);
        BAR; PRIO1; MMAQ(0, 0); PRIO0; ENDPH;
        RD_B(0, 1); STG(1, 0, 1, ktY);
        BAR; PRIO1; MMAQ(0, 1); PRIO0; ENDPH;
        RD_A(0, 1); STG(0, 1, 0, ktX2); STG(0, 1, 1, ktX2);
        BAR; PRIO1; MMAQ(1, 1); MMAQ(1, 0); PRIO0; CHK4; ENDPH;
        // ---- Y tile (buf 1) ----
        RD_A(1, 0); RD_B(1, 0); STG(0, 0, 0, ktX2);
        BAR; PRIO1; MMAQ(0, 0); PRIO0; ENDPH;
        RD_B(1, 1); STG(0, 0, 1, ktX2);
        BAR; PRIO1; MMAQ(0, 1); PRIO0; ENDPH;
        RD_A(1, 1); STG(1, 1, 0, ktY2); STG(1, 1, 1, ktY2);
        BAR; PRIO1; MMAQ(1, 1); MMAQ(1, 0); PRIO0; CHK4; ENDPH;
    }

    // ALL waves' in-flight global_load_lds must land before LDS is reused
    // for C staging (wave w's stage region overlaps wave w-1's buf0-A dest).
    asm volatile("s_waitcnt vmcnt(0)" ::: "memory");
    __builtin_amdgcn_s_barrier();
    __builtin_amdgcn_sched_barrier(0);

    float pts = pts_from_amax(__uint_as_float(*amax_bits));

    // ---- LDS-staged coalesced C-write ----
    // Per wave: private 4 KiB region; per i-block (16 rows x 64 cols f32):
    // scatter acc (col=lane-fragment layout) -> LDS, read back float4,
    // store 256 B contiguous per row (16 lanes x 16 B).
    float* stage = (float*)&sh[0][0][0][0] + w * 1024;
    const int erow = lane >> 4;              // 0..3 (row within 4-row group)
    const int ecol = lane & 15;              // 0..15 (16 B chunk)
    float* Cb = C + (size_t)(bm * 256 + wm * 128) * N + bn * 256 + wn * 64;
#pragma unroll
    for (int i = 0; i < 8; i++) {
        // C/D layout (verified m89/m91): col = lane&15, row = (lane>>4)*4+reg
#pragma unroll
        for (int j = 0; j < 4; j++)
#pragma unroll
            for (int t = 0; t < 4; t++)
                stage[(q * 4 + t) * 64 + j * 16 + r16] = pts * acc[i][j][t];
        asm volatile("s_waitcnt lgkmcnt(0)" ::: "memory");  // writes landed
        __builtin_amdgcn_sched_barrier(0);
#pragma unroll
        for (int k4 = 0; k4 < 4; k4++) {
            float4 vv = *(const float4*)&stage[(k4 * 4 + erow) * 64 + ecol * 4];
            *(float4*)&Cb[(size_t)(i * 16 + k4 * 4 + erow) * N + ecol * 4] = vv;
        }
        asm volatile("s_waitcnt lgkmcnt(0)" ::: "memory");  // reads done (WAR)
        __builtin_amdgcn_sched_barrier(0);
    }
}

// ---- launch --------------------------------------------------------------

extern "C" void kernel_launch(void* const* d_in, const int* in_sizes, int n_in,
                              void* d_out, int out_size, void* d_ws, size_t ws_size,
                              hipStream_t stream) {
    const float* x   = (const float*)d_in[0];
    const int*   wp  = (const int*)d_in[1];
    const float* wsc = (const float*)d_in[2];
    const float* wgs = (const float*)d_in[3];
    float* out = (float*)d_out;

    // workspace layout:
    //   +0      : amax bits (u32, written by amax_fin)
    //   +64     : 2048 float partial maxima
    //   +16384  : A bf16 [M*K]
    //   then    : B bf16 [N*K]
    u32*   amax_bits = (u32*)d_ws;
    float* part      = (float*)((char*)d_ws + 64);
    u16*   aq        = (u16*)((char*)d_ws + 16384);
    u16*   wq        = aq + (size_t)M * K;

    amax_part<<<2048, 256, 0, stream>>>((const float4*)x, part,
                                        wp, wsc, wgs, wq);
    amax_fin<<<1, 1024, 0, stream>>>(part, amax_bits);
    prep<<<2048, 256, 0, stream>>>((const float4*)x, (uint2*)aq, amax_bits);
    gemm_bt<<<512, 512, 0, stream>>>(aq, wq, out, amax_bits);
}